// Round 1
// baseline (36.764 us; speedup 1.0000x reference)
//
#include <hip/hip_runtime.h>

#define NG  8     // groups (heads)
#define DH  8     // channels per group
#define KS  7
#define PAD 3
#define TS  16    // spatial tile (outputs) per block, both dims
#define OW  4     // outputs per thread along W
#define TPW 22    // padded tile extent (TS + KS - 1)
#define LST 24    // LDS row stride in words (16B-aligned rows, even bank spread)
#define CH  64
#define HH  64
#define WW  64

__device__ __forceinline__ int imin(int a, int b) { return a < b ? a : b; }
__device__ __forceinline__ int imax(int a, int b) { return a > b ? a : b; }

__global__ __launch_bounds__(64, 1)
void saconv_kernel(const float* __restrict__ x,
                   const float* __restrict__ wq,
                   const float* __restrict__ wk,
                   const float* __restrict__ wv,
                   const float* __restrict__ relh,
                   const float* __restrict__ relw,
                   float* __restrict__ out) {
  __shared__ float xs[DH][TPW * LST];   // zero-padded x tile, 16.5 KB
  __shared__ float swq[DH * DH];
  __shared__ float swk[DH * DH];
  __shared__ float swv[DH * DH];
  __shared__ float srel[DH * KS];       // rel table for this group's channels

  const int tx  = threadIdx.x;          // 0..3  (quad of output columns)
  const int ty  = threadIdx.y;          // 0..15 (output row)
  const int tid = ty * OW + tx;         // 0..63 == lane id
  const int bz  = blockIdx.z;
  const int b   = bz >> 3;
  const int g   = bz & 7;
  const int h0  = blockIdx.y * TS;
  const int w0  = blockIdx.x * TS;

  // ---- stage weights + rel table ----
  if (tid < DH * DH) {
    swq[tid] = wq[g * DH * DH + tid];
    swk[tid] = wk[g * DH * DH + tid];
    swv[tid] = wv[g * DH * DH + tid];
  }
  if (tid < DH * KS) {
    int c = tid / KS, t = tid - c * KS;
    int gc = g * DH + c;               // global channel
    srel[tid] = (g < 4) ? relh[gc * KS + t] : relw[(gc - 32) * KS + t];
  }

  // ---- stage zero-padded x tile: xs[ci][row*LST+col] = x[b, g*8+ci, h0+row-3, w0+col-3] ----
  const float* xb = x + (size_t)(b * CH + g * DH) * (HH * WW);
  #pragma unroll
  for (int kk = 0; kk < 61; kk++) {
    int idx = tid + kk * 64;
    if (kk < 60 || idx < DH * TPW * TPW) {
      int ci  = idx / (TPW * TPW);
      int r   = idx - ci * (TPW * TPW);
      int row = r / TPW;
      int col = r - row * TPW;
      int yy = h0 + row - PAD;
      int xx = w0 + col - PAD;
      bool inb = (yy >= 0) & (yy < HH) & (xx >= 0) & (xx < WW);
      int cy = imin(imax(yy, 0), HH - 1);
      int cx = imin(imax(xx, 0), WW - 1);
      float v = xb[(ci * HH + cy) * WW + cx];   // clamped load (no divergence)
      xs[ci][row * LST + col] = inb ? v : 0.0f;
    }
  }
  __syncthreads();

  // ---- q for this thread's 4 outputs, then fold: qk = Wk^T q, rq = rel^T q ----
  float q_[OW][DH];
  #pragma unroll
  for (int o = 0; o < OW; o++) {
    float xc[DH];
    #pragma unroll
    for (int ci = 0; ci < DH; ci++)
      xc[ci] = xs[ci][(ty + PAD) * LST + tx * OW + o + PAD];
    #pragma unroll
    for (int c = 0; c < DH; c++) {
      float a = 0.f;
      #pragma unroll
      for (int ci = 0; ci < DH; ci++)
        a = fmaf(swq[c * DH + ci], xc[ci], a);
      q_[o][c] = a;
    }
  }

  float qk[OW][DH];
  #pragma unroll
  for (int o = 0; o < OW; o++)
    #pragma unroll
    for (int ci = 0; ci < DH; ci++) {
      float a = 0.f;
      #pragma unroll
      for (int c = 0; c < DH; c++)
        a = fmaf(q_[o][c], swk[c * DH + ci], a);
      qk[o][ci] = a;
    }

  float rq[OW][KS];
  #pragma unroll
  for (int o = 0; o < OW; o++)
    #pragma unroll
    for (int t = 0; t < KS; t++) {
      float a = 0.f;
      #pragma unroll
      for (int c = 0; c < DH; c++)
        a = fmaf(q_[o][c], srel[c * KS + t], a);
      rq[o][t] = a;
    }

  // ---- online-softmax window loop ----
  const float scale = 0.35355339059327373f;  // sqrt(g/Cout) = sqrt(1/8)
  const bool useI = (g < 4);                 // rel_h half -> depends on window row i

  float m[OW], s[OW], xa[OW][DH];
  #pragma unroll
  for (int o = 0; o < OW; o++) {
    m[o] = -1e30f;
    s[o] = 0.f;
    #pragma unroll
    for (int ci = 0; ci < DH; ci++) xa[o][ci] = 0.f;
  }

  #pragma unroll
  for (int i = 0; i < KS; i++) {
    const int rowoff = (ty + i) * LST + tx * OW;   // 16B-aligned word offset
    // load the 12-word row segment for all 8 channels (3x ds_read_b128 each)
    float xr[DH][12];
    #pragma unroll
    for (int ci = 0; ci < DH; ci++) {
      const float* bp = &xs[ci][rowoff];
      float4 a0 = *(const float4*)(bp);
      float4 a1 = *(const float4*)(bp + 4);
      float4 a2 = *(const float4*)(bp + 8);
      xr[ci][0] = a0.x;  xr[ci][1] = a0.y;  xr[ci][2]  = a0.z;  xr[ci][3]  = a0.w;
      xr[ci][4] = a1.x;  xr[ci][5] = a1.y;  xr[ci][6]  = a1.z;  xr[ci][7]  = a1.w;
      xr[ci][8] = a2.x;  xr[ci][9] = a2.y;  xr[ci][10] = a2.z;  xr[ci][11] = a2.w;
    }

    // logits for this window row
    float lg[OW][KS];
    #pragma unroll
    for (int o = 0; o < OW; o++) {
      #pragma unroll
      for (int j = 0; j < KS; j++) {
        float d = 0.f;
        #pragma unroll
        for (int ci = 0; ci < DH; ci++)
          d = fmaf(qk[o][ci], xr[ci][o + j], d);
        lg[o][j] = (d + (useI ? rq[o][i] : rq[o][j])) * scale;
      }
    }

    // online softmax update + weighted-x accumulation
    #pragma unroll
    for (int o = 0; o < OW; o++) {
      float rmax = lg[o][0];
      #pragma unroll
      for (int j = 1; j < KS; j++) rmax = fmaxf(rmax, lg[o][j]);
      float mn   = fmaxf(m[o], rmax);
      float corr = __expf(m[o] - mn);      // first row: exp(-huge) == 0
      m[o] = mn;
      float e[KS], se = 0.f;
      #pragma unroll
      for (int j = 0; j < KS; j++) { e[j] = __expf(lg[o][j] - mn); se += e[j]; }
      s[o] = s[o] * corr + se;
      #pragma unroll
      for (int ci = 0; ci < DH; ci++) {
        float a = xa[o][ci] * corr;
        #pragma unroll
        for (int j = 0; j < KS; j++)
          a = fmaf(e[j], xr[ci][o + j], a);
        xa[o][ci] = a;
      }
    }
  }

  // ---- epilogue: out = Wv * (xa / s), vectorized float4 store ----
  #pragma unroll
  for (int o = 0; o < OW; o++) {
    float inv = 1.0f / s[o];
    #pragma unroll
    for (int ci = 0; ci < DH; ci++) xa[o][ci] *= inv;
  }

  const int h = h0 + ty;
  const int wbase = w0 + tx * OW;
  #pragma unroll
  for (int c = 0; c < DH; c++) {
    float ov[OW];
    #pragma unroll
    for (int o = 0; o < OW; o++) {
      float a = 0.f;
      #pragma unroll
      for (int ci = 0; ci < DH; ci++)
        a = fmaf(swv[c * DH + ci], xa[o][ci], a);
      ov[o] = a;
    }
    float4 v4 = make_float4(ov[0], ov[1], ov[2], ov[3]);
    *(float4*)(&out[((size_t)(b * CH + g * DH + c) * HH + h) * WW + wbase]) = v4;
  }
}

extern "C" void kernel_launch(void* const* d_in, const int* in_sizes, int n_in,
                              void* d_out, int out_size, void* d_ws, size_t ws_size,
                              hipStream_t stream) {
  const float* x    = (const float*)d_in[0];
  // d_in[1] = r, unused by the reference computation
  const float* wq   = (const float*)d_in[2];
  const float* wk   = (const float*)d_in[3];
  const float* wv   = (const float*)d_in[4];
  const float* relh = (const float*)d_in[5];
  const float* relw = (const float*)d_in[6];
  float* out = (float*)d_out;

  const int B = in_sizes[0] / (CH * HH * WW);   // 8
  dim3 grid(WW / TS, HH / TS, B * NG);          // 4 x 4 x 64 = 1024 blocks
  dim3 block(OW, TS, 1);                        // 64 threads = 1 wave
  saconv_kernel<<<grid, block, 0, stream>>>(x, wq, wk, wv, relh, relw, out);
}